// Round 3
// baseline (949.176 us; speedup 1.0000x reference)
//
#include <hip/hip_runtime.h>
#include <hip/hip_fp16.h>
#include <math.h>

#define NN 50000
#define EE 800000
#define HH 128
#define KIT 10
#define NHF (NN * HH)     // 6,400,000 elements per snapshot
#define CC 64             // edge chunks
#define CH 12500          // edges per chunk (divisible by 4; byte offset 16B-aligned)
#define RRH 4             // node ranges per mode
#define NRH 12500         // nodes per range (50KB LDS)
#define GPROP 1536        // persistent prop grid: 6 blocks/CU x 256 CU

typedef _Float16 half8 __attribute__((ext_vector_type(8)));
typedef _Float16 half4v __attribute__((ext_vector_type(4)));
typedef float floatx4 __attribute__((ext_vector_type(4)));

static_assert(NN % 16 == 0, "row tiles must be exact");

__device__ __forceinline__ float gelu_exact(float x) {
  return 0.5f * x * (1.f + erff(x * 0.70710678118654752f));
}

// typed 4-float load/store helpers (fp32 or fp16 storage)
__device__ __forceinline__ float4 ld4(const float* p) { return *(const float4*)p; }
__device__ __forceinline__ float4 ld4(const __half* p) {
  const __half2* q = (const __half2*)p;
  float2 lo = __half22float2(q[0]);
  float2 hi = __half22float2(q[1]);
  return make_float4(lo.x, lo.y, hi.x, hi.y);
}
__device__ __forceinline__ void st1(float* p, float v) { *p = v; }
__device__ __forceinline__ void st1(__half* p, float v) { *p = __float2half_rn(v); }

// ---------------- graph preprocessing (NO global atomics) ----------------
__global__ __launch_bounds__(256) void hist2_kernel(const int* __restrict__ ei,
                                                    const float* __restrict__ ew,
                                                    int* __restrict__ pdeg,
                                                    float* __restrict__ pwsum,
                                                    int* __restrict__ rank) {
  __shared__ int hist[NRH];
  const int c = blockIdx.x;
  const int z = blockIdx.y;
  const bool isdeg = (z < RRH);
  const int lo = (isdeg ? z : z - RRH) * NRH;
  for (int i = threadIdx.x; i < NRH; i += 256) hist[i] = 0;   // 0 bits == 0.f
  __syncthreads();
  const int e0 = c * CH;
  if (isdeg) {
    const int4* d4 = (const int4*)(ei + (size_t)EE + e0);
    for (int i = threadIdx.x; i < CH / 4; i += 256) {
      int4 d = d4[i];
      int e = e0 + i * 4;
      unsigned u0 = (unsigned)(d.x - lo), u1 = (unsigned)(d.y - lo);
      unsigned u2 = (unsigned)(d.z - lo), u3 = (unsigned)(d.w - lo);
      if (u0 < NRH) rank[e]     = atomicAdd(&hist[u0], 1);
      if (u1 < NRH) rank[e + 1] = atomicAdd(&hist[u1], 1);
      if (u2 < NRH) rank[e + 2] = atomicAdd(&hist[u2], 1);
      if (u3 < NRH) rank[e + 3] = atomicAdd(&hist[u3], 1);
    }
    __syncthreads();
    for (int i = threadIdx.x; i < NRH; i += 256)
      pdeg[(size_t)c * NN + lo + i] = hist[i];
  } else {
    float* whist = (float*)hist;
    const int4* s4 = (const int4*)(ei + e0);
    const float4* w4 = (const float4*)(ew + e0);
    for (int i = threadIdx.x; i < CH / 4; i += 256) {
      int4 s = s4[i];
      float4 w = w4[i];
      unsigned u0 = (unsigned)(s.x - lo), u1 = (unsigned)(s.y - lo);
      unsigned u2 = (unsigned)(s.z - lo), u3 = (unsigned)(s.w - lo);
      if (u0 < NRH) atomicAdd(&whist[u0], w.x);
      if (u1 < NRH) atomicAdd(&whist[u1], w.y);
      if (u2 < NRH) atomicAdd(&whist[u2], w.z);
      if (u3 < NRH) atomicAdd(&whist[u3], w.w);
    }
    __syncthreads();
    for (int i = threadIdx.x; i < NRH; i += 256)
      pwsum[(size_t)c * NN + lo + i] = whist[i];
  }
}

// per-node: deg = sum over chunks (pdeg -> in-place exclusive chunk prefix),
// wsum = sum over chunks; block-reduce PADDED deg -> bsum (rows padded to mult of 8).
__global__ __launch_bounds__(256) void reduce_kernel(int* __restrict__ pdeg,
                                                     const float* __restrict__ pwsum,
                                                     int* __restrict__ deg,
                                                     float* __restrict__ wsum,
                                                     int* __restrict__ bsum) {
  int node = blockIdx.x * 256 + threadIdx.x;
  int acc = 0; float wacc = 0.f;
  if (node < NN) {
    for (int c = 0; c < CC; ++c) {
      size_t idx = (size_t)c * NN + node;
      int t = pdeg[idx];
      pdeg[idx] = acc;        // exclusive prefix over chunks
      acc += t;
      wacc += pwsum[idx];
    }
    deg[node] = acc;          // real degree
    wsum[node] = wacc;
  }
  __shared__ int red[256];
  red[threadIdx.x] = (node < NN) ? ((acc + 7) & ~7) : 0;   // padded degree
  __syncthreads();
  for (int off = 128; off > 0; off >>= 1) {
    if (threadIdx.x < off) red[threadIdx.x] += red[threadIdx.x + off];
    __syncthreads();
  }
  if (threadIdx.x == 0) bsum[blockIdx.x] = red[0];
}

__global__ __launch_bounds__(256) void scan2_kernel(const int* __restrict__ bsum,
                                                    int* __restrict__ boff,
                                                    int* __restrict__ row_start, int nb, int n) {
  __shared__ int buf[256];
  int tid = threadIdx.x;
  int v = (tid < nb) ? bsum[tid] : 0;
  buf[tid] = v;
  __syncthreads();
  for (int off = 1; off < 256; off <<= 1) {
    int t = (tid >= off) ? buf[tid - off] : 0;
    __syncthreads();
    buf[tid] += t;
    __syncthreads();
  }
  if (tid < nb) boff[tid] = buf[tid] - v;  // exclusive prefix
  if (tid == 255) row_start[n] = buf[255];
}

// scan over PADDED degrees -> row_start
__global__ __launch_bounds__(256) void scan3_kernel(const int* __restrict__ deg,
                                                    const int* __restrict__ boff,
                                                    int* __restrict__ row_start, int n) {
  __shared__ int buf[256];
  int tid = threadIdx.x;
  int i = blockIdx.x * 256 + tid;
  int v = (i < n) ? ((deg[i] + 7) & ~7) : 0;
  buf[tid] = v;
  __syncthreads();
  for (int off = 1; off < 256; off <<= 1) {
    int t = (tid >= off) ? buf[tid - off] : 0;
    __syncthreads();
    buf[tid] += t;
    __syncthreads();
  }
  if (i < n) row_start[i] = boff[blockIdx.x] + buf[tid] - v;
}

__global__ __launch_bounds__(256) void csr_fill_kernel(const int* __restrict__ ei,
                                                       const float* __restrict__ ew,
                                                       const float* __restrict__ wsum,
                                                       const int* __restrict__ row_start,
                                                       const int* __restrict__ pdeg_excl,
                                                       const int* __restrict__ rank,
                                                       int2* __restrict__ csr, int e_cnt) {
  int e = blockIdx.x * 256 + threadIdx.x;
  if (e >= e_cnt) return;
  int c = e / CH;
  int src = ei[e], dst = ei[EE + e];
  float ws = wsum[src];
  ws = ws < 1.f ? 1.f : ws;
  float v = 0.9f * ew[e] / ws;            // (1-ALPHA) * enorm folded together
  int pos = row_start[dst] + pdeg_excl[(size_t)c * NN + dst] + rank[e];
  csr[pos] = make_int2(src, __float_as_int(v));
}

// fill pad slots [row_start+deg, row_start_next) with (src=0, w=+0.f): contributes 0.
__global__ __launch_bounds__(256) void pad_fill_kernel(const int* __restrict__ deg,
                                                       const int* __restrict__ row_start,
                                                       long* __restrict__ csr) {
  int node = blockIdx.x * 256 + threadIdx.x;
  if (node >= NN) return;
  int s = row_start[node] + deg[node];
  int e = row_start[node + 1];
  for (int i = s; i < e; ++i) csr[i] = 0;
}

// ---------------- propagation: plane-split persistent kernel ----------------
// h layout: [4 planes][NN][32 fp16]. Each plane = 3.2 MB -> fits per-XCD L2 (4 MB),
// so random gathers become L2 hits instead of L3 traffic. Persistent grid (6/CU);
// every wave loops planes in ORDER -> all resident waves touch the same plane.
// Wave = 4 groups x 16 lanes; 4 consecutive nodes per unit share one contiguous
// padded CSR stream; a 4-edge sub-batch never crosses a node boundary (pad=8).
#define SELFMA(CEV, VV, IO)                                                        \
  {                                                                                \
    float w_ = __int_as_float((int)((CEV) >> 32));                                 \
    int sel_ = ((IO) >= e1) + ((IO) >= e2) + ((IO) >= e3);                         \
    if (sel_ == 0)      { acc0.x = fmaf(w_, (VV).x, acc0.x); acc0.y = fmaf(w_, (VV).y, acc0.y); } \
    else if (sel_ == 1) { acc1.x = fmaf(w_, (VV).x, acc1.x); acc1.y = fmaf(w_, (VV).y, acc1.y); } \
    else if (sel_ == 2) { acc2.x = fmaf(w_, (VV).x, acc2.x); acc2.y = fmaf(w_, (VV).y, acc2.y); } \
    else                { acc3.x = fmaf(w_, (VV).x, acc3.x); acc3.y = fmaf(w_, (VV).y, acc3.y); } \
  }

__global__ __launch_bounds__(256, 6) void prop_plane_kernel(
    const __half* __restrict__ h_cur, const __half* __restrict__ base,
    const int* __restrict__ row_start, const long* __restrict__ csr,
    __half* __restrict__ h_next) {
  const int W = GPROP * 4;                        // total waves
  const int wid = (int)blockIdx.x * 4 + (int)(threadIdx.x >> 6);
  const int lane = threadIdx.x & 63;
  const int g = lane >> 4, l = lane & 15;
  const int UNITS = NN / 4;                       // 12500

  for (int plane = 0; plane < 4; ++plane) {
    const __half2* hp = (const __half2*)(h_cur + (size_t)plane * NN * 32);
    const __half2* bp = (const __half2*)(base + (size_t)plane * NN * 32);
    __half2* np = (__half2*)(h_next + (size_t)plane * NN * 32);
    for (int u = wid; u < UNITS; u += W) {
      int n0 = u * 4;
      int s  = __builtin_amdgcn_readfirstlane(row_start[n0]);
      int e1 = __builtin_amdgcn_readfirstlane(row_start[n0 + 1]);
      int e2 = __builtin_amdgcn_readfirstlane(row_start[n0 + 2]);
      int e3 = __builtin_amdgcn_readfirstlane(row_start[n0 + 3]);
      int e4 = __builtin_amdgcn_readfirstlane(row_start[n0 + 4]);
      float2 acc0 = make_float2(0.f, 0.f), acc1 = make_float2(0.f, 0.f);
      float2 acc2 = make_float2(0.f, 0.f), acc3 = make_float2(0.f, 0.f);
      int nb = (e4 - s) >> 2;                     // 4-edge sub-batches (even)
      int nfull = nb >> 2;                        // super-batches of 4 sub-batches
      int i = s, ic = s;
      if (nfull > 0) {
        long cur[4];
#pragma unroll
        for (int j = 0; j < 4; ++j) cur[j] = csr[i + j * 4 + g];
        i += 16;
        for (int b = 1; b < nfull; ++b) {
          long nxt[4];
#pragma unroll
          for (int j = 0; j < 4; ++j) nxt[j] = csr[i + j * 4 + g];
          i += 16;
          float2 v[4];
#pragma unroll
          for (int j = 0; j < 4; ++j)
            v[j] = __half22float2(hp[(size_t)(int)cur[j] * 16 + l]);
#pragma unroll
          for (int j = 0; j < 4; ++j) SELFMA(cur[j], v[j], ic + j * 4);
#pragma unroll
          for (int j = 0; j < 4; ++j) cur[j] = nxt[j];
          ic += 16;
        }
        float2 v[4];
#pragma unroll
        for (int j = 0; j < 4; ++j)
          v[j] = __half22float2(hp[(size_t)(int)cur[j] * 16 + l]);
#pragma unroll
        for (int j = 0; j < 4; ++j) SELFMA(cur[j], v[j], ic + j * 4);
        ic += 16;
      }
      // tail (nb % 4 sub-batches, <= 2)
      for (; i < e4; i += 4) {
        long ce = csr[i + g];
        float2 v = __half22float2(hp[(size_t)(int)ce * 16 + l]);
        SELFMA(ce, v, i);
      }
      // cross-group reduction: sum partials over g (lanes l, l+16, l+32, l+48)
      acc0.x += __shfl_xor(acc0.x, 16); acc0.y += __shfl_xor(acc0.y, 16);
      acc0.x += __shfl_xor(acc0.x, 32); acc0.y += __shfl_xor(acc0.y, 32);
      acc1.x += __shfl_xor(acc1.x, 16); acc1.y += __shfl_xor(acc1.y, 16);
      acc1.x += __shfl_xor(acc1.x, 32); acc1.y += __shfl_xor(acc1.y, 32);
      acc2.x += __shfl_xor(acc2.x, 16); acc2.y += __shfl_xor(acc2.y, 16);
      acc2.x += __shfl_xor(acc2.x, 32); acc2.y += __shfl_xor(acc2.y, 32);
      acc3.x += __shfl_xor(acc3.x, 16); acc3.y += __shfl_xor(acc3.y, 16);
      acc3.x += __shfl_xor(acc3.x, 32); acc3.y += __shfl_xor(acc3.y, 32);
      float2 r = (g == 0) ? acc0 : (g == 1) ? acc1 : (g == 2) ? acc2 : acc3;
      float2 bb = __half22float2(bp[(size_t)(n0 + g) * 16 + l]);
      np[(size_t)(n0 + g) * 16 + l] = __float22half2_rn(
          make_float2(fmaf(0.1f, bb.x, r.x), fmaf(0.1f, bb.y, r.y)));
    }
  }
}

// ---------------- MFMA dense v2: out[n][j] = act(sum_k X[n][k] * W[j][k] + ...) ----------
// PIN: inputs in plane layout [4][NN][32] fp16 (A-fragment 16B chunks never cross a
// 32-dim plane boundary since c = s*32 + q*8). POUT: output written in plane layout.
template <int K, int KA, int JP, int JR, int ACT, bool RESID, typename IT, typename OT,
          bool PIN = false, bool POUT = false>
__global__ __launch_bounds__(256) void mfma_dense2(
    const IT* __restrict__ Xa, const IT* __restrict__ Xb,
    const float* __restrict__ W, const float* __restrict__ lb,
    const float* __restrict__ bg, const float* __restrict__ bb,
    const float* __restrict__ bm, const float* __restrict__ bv,
    const OT* __restrict__ resid, OT* __restrict__ out) {
  static_assert(K % 32 == 0 && KA % 32 == 0 && JP % 16 == 0, "");
  constexpr int JT = JP / 16;      // 16-col MFMA tiles
  constexpr int NS = K / 32;       // K-slices of 32
  constexpr bool ISF = __is_same(IT, float);
  __shared__ _Float16 wL[JP][K];   // swizzled: 16B chunk c stored at chunk (c ^ (j&7))

  const int tid = threadIdx.x;
  const int wv = tid >> 6, lane = tid & 63;
  const int q = lane >> 4, m = lane & 15;
  const int t = blockIdx.x * 4 + wv;           // tile id (16 rows)
  const bool active = (t < NN / 16);
  const int row = t * 16 + m;

  // ---- issue per-lane A-fragment loads (direct global, 16B each) ----
  half8  a[ISF ? 1 : NS];
  float4 af0[ISF ? NS : 1], af1[ISF ? NS : 1];
  if (active) {
#pragma unroll
    for (int s = 0; s < NS; ++s) {
      int c = s * 32 + q * 8;
      if constexpr (ISF) {
        const float* p = (const float*)Xa + (size_t)row * K + c;
        af0[s] = *(const float4*)p;
        af1[s] = *(const float4*)(p + 4);
      } else if constexpr (PIN) {
        int cc = (c < KA) ? c : c - KA;
        const __half* Xp = (c < KA) ? (const __half*)Xa : (const __half*)Xb;
        const __half* p = Xp + (size_t)(cc >> 5) * (NN * 32) + (size_t)row * 32 + (cc & 31);
        a[s] = *(const half8*)p;
      } else {
        const __half* p = (c < KA) ? (const __half*)Xa + (size_t)row * KA + c
                                   : (const __half*)Xb + (size_t)row * (K - KA) + (c - KA);
        a[s] = *(const half8*)p;
      }
    }
  }

  // ---- stage W: fp32 -> fp16, swizzled LDS; zero-fill rows j >= JR ----
  constexpr int C4 = K / 4;
  for (int idx = tid; idx < JP * C4; idx += 256) {
    int j = idx / C4;
    int c4 = (idx % C4) * 4;
    float4 v = make_float4(0.f, 0.f, 0.f, 0.f);
    if (j < JR) v = *(const float4*)&W[(size_t)j * K + c4];
    int cs = ((((c4 >> 3) ^ (j & 7)) << 3) | (c4 & 7));
    *(half4v*)&wL[j][cs] = (half4v){(_Float16)v.x, (_Float16)v.y,
                                    (_Float16)v.z, (_Float16)v.w};
  }
  __syncthreads();

  if (!active) return;

  floatx4 acc[JT];
#pragma unroll
  for (int jt = 0; jt < JT; ++jt) acc[jt] = (floatx4)(0.f);

#pragma unroll
  for (int s = 0; s < NS; ++s) {
    half8 av;
    if constexpr (ISF) {
      float4 f0 = af0[s], f1 = af1[s];
      av = (half8){(_Float16)f0.x, (_Float16)f0.y, (_Float16)f0.z, (_Float16)f0.w,
                   (_Float16)f1.x, (_Float16)f1.y, (_Float16)f1.z, (_Float16)f1.w};
    } else {
      av = a[s];
    }
    int kq = s * 4 + q;                        // 16B chunk index within row
#pragma unroll
    for (int jt = 0; jt < JT; ++jt) {
      int j = jt * 16 + m;
      half8 b = *(const half8*)&wL[j][(kq ^ (j & 7)) << 3];
      acc[jt] = __builtin_amdgcn_mfma_f32_16x16x32_f16(av, b, acc[jt], 0, 0, 0);
    }
  }

  // epilogue: lane holds col j = jt*16 + m, rows q*4 + reg
#pragma unroll
  for (int jt = 0; jt < JT; ++jt) {
    int j = jt * 16 + m;
    if (j >= JR) continue;
    float sc = 0.f, sh;
    if (ACT == 1) {
      sc = bg[j] * rsqrtf(bv[j] + 1e-5f);
      sh = (lb[j] - bm[j]) * sc + bb[j];
    } else {
      sh = lb[j];
    }
#pragma unroll
    for (int reg = 0; reg < 4; ++reg) {
      int r = t * 16 + q * 4 + reg;
      float aa = acc[jt][reg];
      float y;
      if (ACT == 0)      y = aa + sh;
      else if (ACT == 1) y = fmaxf(fmaf(aa, sc, sh), 0.f);
      else               y = gelu_exact(aa + sh);
      if (RESID) y += (float)resid[(size_t)r * JR + j];
      if constexpr (POUT)
        st1(&out[(size_t)(j >> 5) * (NN * 32) + (size_t)r * 32 + (j & 31)], y);
      else
        st1(&out[(size_t)r * JR + j], y);
    }
  }
}

// ---------------- att2 (64 -> 11) + softmax, one thread per node ----------------
__global__ __launch_bounds__(64) void att2_softmax_kernel(const __half* __restrict__ g,
                                                          const float* __restrict__ W2,
                                                          const float* __restrict__ b2,
                                                          float* __restrict__ attw, int n_rows) {
  __shared__ float gl[64][65];
  int r0 = blockIdx.x * 64;
  for (int idx = threadIdx.x; idx < 64 * 16; idx += 64) {
    int r = idx >> 4, c4 = (idx & 15) * 4;
    float4 v = make_float4(0.f, 0.f, 0.f, 0.f);
    if (r0 + r < n_rows) v = ld4(&g[(size_t)(r0 + r) * 64 + c4]);
    gl[r][c4] = v.x; gl[r][c4 + 1] = v.y; gl[r][c4 + 2] = v.z; gl[r][c4 + 3] = v.w;
  }
  __syncthreads();
  int r = threadIdx.x;
  int n = r0 + r;
  if (n >= n_rows) return;
  float a[KIT + 1];
#pragma unroll
  for (int j = 0; j < KIT + 1; ++j) {
    float acc = b2[j];
#pragma unroll
    for (int k = 0; k < 64; ++k) acc = fmaf(gl[r][k], W2[j * 64 + k], acc);
    a[j] = acc;
  }
  float mx = a[0];
#pragma unroll
  for (int j = 1; j < KIT + 1; ++j) mx = fmaxf(mx, a[j]);
  float s = 0.f;
#pragma unroll
  for (int j = 0; j < KIT + 1; ++j) { a[j] = expf(a[j] - mx); s += a[j]; }
  float inv = 1.f / s;
#pragma unroll
  for (int j = 0; j < KIT + 1; ++j) attw[n * 16 + j] = a[j] * inv;
}

// ---------------- fuse: fused[n][128] = sum_k attw[n][k] * XS_k[n] ----------------
// XS in plane layout; lane's dims = (plane q, pair l) == global dim 2*lane -> row write.
__global__ __launch_bounds__(256) void fused_gather_kernel(const __half* __restrict__ XS,
                                                           const float* __restrict__ attw,
                                                           __half* __restrict__ fused) {
  int node = __builtin_amdgcn_readfirstlane((int)blockIdx.x * 4 + (int)(threadIdx.x >> 6));
  if (node >= NN) return;
  int lane = threadIdx.x & 63;
  int q = lane >> 4, l = lane & 15;
  size_t pidx = (size_t)q * (NN * 16) + (size_t)node * 16 + l;
  float ax = 0.f, ay = 0.f;
#pragma unroll
  for (int k = 0; k <= KIT; ++k) {
    float wk = attw[node * 16 + k];   // wave-uniform -> s_load
    float2 v = __half22float2(((const __half2*)(XS + (size_t)k * NHF))[pidx]);
    ax = fmaf(wk, v.x, ax);
    ay = fmaf(wk, v.y, ay);
  }
  ((__half2*)fused)[(size_t)node * 64 + lane] = __float22half2_rn(make_float2(ax, ay));
}

// recompute-path variant: fused (+)= attw[:,k] * h (h plane fp16, fused fp32 row)
__global__ __launch_bounds__(256) void fused_accum_kernel(const __half* __restrict__ h,
                                                          const float* __restrict__ attw,
                                                          float* __restrict__ fused, int k) {
  int node = __builtin_amdgcn_readfirstlane((int)blockIdx.x * 4 + (int)(threadIdx.x >> 6));
  if (node >= NN) return;
  int lane = threadIdx.x & 63;
  int q = lane >> 4, l = lane & 15;
  float wk = attw[node * 16 + k];
  float2 v = __half22float2(
      ((const __half2*)h)[(size_t)q * (NN * 16) + (size_t)node * 16 + l]);
  float2 o;
  if (k == 0) {
    o = make_float2(wk * v.x, wk * v.y);
  } else {
    float2 f = ((const float2*)fused)[(size_t)node * 64 + lane];
    o = make_float2(fmaf(wk, v.x, f.x), fmaf(wk, v.y, f.y));
  }
  ((float2*)fused)[(size_t)node * 64 + lane] = o;
}

extern "C" void kernel_launch(void* const* d_in, const int* in_sizes, int n_in,
                              void* d_out, int out_size, void* d_ws, size_t ws_size,
                              hipStream_t stream) {
  (void)in_sizes; (void)n_in; (void)out_size;
  const float* x      = (const float*)d_in[0];
  const int*   ei     = (const int*)d_in[1];
  const float* ew     = (const float*)d_in[2];
  const float* lin1_w = (const float*)d_in[3];
  const float* lin1_b = (const float*)d_in[4];
  const float* bn1_g  = (const float*)d_in[5];
  const float* bn1_b  = (const float*)d_in[6];
  const float* bn1_m  = (const float*)d_in[7];
  const float* bn1_v  = (const float*)d_in[8];
  const float* lin2_w = (const float*)d_in[9];
  const float* lin2_b = (const float*)d_in[10];
  const float* bn2_g  = (const float*)d_in[11];
  const float* bn2_b  = (const float*)d_in[12];
  const float* bn2_m  = (const float*)d_in[13];
  const float* bn2_v  = (const float*)d_in[14];
  const float* att1_w = (const float*)d_in[15];
  const float* att1_b = (const float*)d_in[16];
  const float* att2_w = (const float*)d_in[17];
  const float* att2_b = (const float*)d_in[18];
  const float* head1_w= (const float*)d_in[19];
  const float* head1_b= (const float*)d_in[20];
  const float* bn3_g  = (const float*)d_in[21];
  const float* bn3_b  = (const float*)d_in[22];
  const float* bn3_m  = (const float*)d_in[23];
  const float* bn3_v  = (const float*)d_in[24];
  const float* head2_w= (const float*)d_in[25];
  const float* head2_b= (const float*)d_in[26];
  float* out = (float*)d_out;

  char* p = (char*)d_ws;
  auto alloc = [&](size_t bytes) -> void* {
    void* r = (void*)p;
    p += (bytes + 255) & ~(size_t)255;
    return r;
  };
  // persistent buffers (live across whole launch)
  int*   row_start= (int*)alloc((size_t)(NN + 1) * 4);
  int*   bsum     = (int*)alloc((size_t)256 * 4);
  int*   boff     = (int*)alloc((size_t)256 * 4);
  int*   deg      = (int*)alloc((size_t)NN * 4);
  float* wsum     = (float*)alloc((size_t)NN * 4);
  long*  csr      = (long*)alloc(((size_t)EE + 8 * NN) * 8);  // padded rows (<=7/node)
  __half* gbuf    = (__half*)alloc((size_t)NN * 64 * 2);
  float* attw     = (float*)alloc((size_t)NN * 16 * 4);
  __half* h1      = (__half*)alloc((size_t)NHF * 2);
  __half* fusedH  = (__half*)alloc((size_t)NHF * 2);
  __half* zbuf    = (__half*)alloc((size_t)NN * 64 * 2);
  size_t common = (size_t)(p - (char*)d_ws);
  size_t stored_need = common + (size_t)(KIT + 1) * NHF * 2 + 4096;
  bool stored = ws_size >= stored_need;

  // preprocessing temporaries overlay XS[8..10] (dead until prop k=7) in stored path.
  __half* XS = nullptr;
  int* pdeg; float* pwsum; int* rank;
  if (stored) {
    XS = (__half*)alloc((size_t)(KIT + 1) * NHF * 2);
    char* ovl = (char*)(XS + (size_t)8 * NHF);
    pdeg  = (int*)ovl;
    pwsum = (float*)(ovl + (size_t)CC * NN * 4);
    rank  = (int*)(ovl + 2 * (size_t)CC * NN * 4);
  } else {
    pdeg  = (int*)alloc((size_t)CC * NN * 4);
    pwsum = (float*)alloc((size_t)CC * NN * 4);
    rank  = (int*)alloc((size_t)EE * 4);
  }

  const int GE  = (EE + 255) / 256;          // edge-parallel grid
  const int GN  = (NN + 255) / 256;          // node-parallel grid (196)
  const int GT  = (NN / 16 + 3) / 4;         // dense v2 grid: 3125 wave-tiles -> 782 blocks
  const int GP  = (NN + 3) / 4;              // wave-per-node grids (12500)
  const int GA  = (NN + 63) / 64;            // att2 grid

  // graph preprocessing (atomic-free)
  hist2_kernel<<<dim3(CC, 2 * RRH), 256, 0, stream>>>(ei, ew, pdeg, pwsum, rank);
  reduce_kernel<<<GN, 256, 0, stream>>>(pdeg, pwsum, deg, wsum, bsum);
  scan2_kernel<<<1, 256, 0, stream>>>(bsum, boff, row_start, GN, NN);
  scan3_kernel<<<GN, 256, 0, stream>>>(deg, boff, row_start, NN);
  csr_fill_kernel<<<GE, 256, 0, stream>>>(ei, ew, wsum, row_start, pdeg, rank,
                                          (int2*)csr, EE);
  pad_fill_kernel<<<GN, 256, 0, stream>>>(deg, row_start, csr);

  if (stored) {
    mfma_dense2<128, 128, 128, 128, 1, false, float, __half><<<GT, 256, 0, stream>>>(
        x, (const float*)nullptr, lin1_w, lin1_b, bn1_g, bn1_b, bn1_m, bn1_v, nullptr, h1);
    mfma_dense2<128, 128, 128, 128, 1, true, __half, __half, false, true>
        <<<GT, 256, 0, stream>>>(
        h1, (const __half*)nullptr, lin2_w, lin2_b, bn2_g, bn2_b, bn2_m, bn2_v, h1, XS);
    for (int k = 0; k < KIT; ++k) {
      prop_plane_kernel<<<GPROP, 256, 0, stream>>>(XS + (size_t)k * NHF, XS, row_start,
                                                   csr, XS + (size_t)(k + 1) * NHF);
    }
    mfma_dense2<256, 128, 64, 64, 2, false, __half, __half, true, false>
        <<<GT, 256, 0, stream>>>(
        XS, XS + (size_t)KIT * NHF, att1_w, att1_b, nullptr, nullptr, nullptr, nullptr,
        nullptr, gbuf);
    att2_softmax_kernel<<<GA, 64, 0, stream>>>(gbuf, att2_w, att2_b, attw, NN);
    fused_gather_kernel<<<GP, 256, 0, stream>>>(XS, attw, fusedH);
    mfma_dense2<128, 128, 64, 64, 1, false, __half, __half><<<GT, 256, 0, stream>>>(
        fusedH, (const __half*)nullptr, head1_w, head1_b, bn3_g, bn3_b, bn3_m, bn3_v,
        nullptr, zbuf);
  } else {
    float*  fusedF = (float*)alloc((size_t)NHF * 4);
    __half* base   = (__half*)alloc((size_t)NHF * 2);
    __half* hA     = (__half*)alloc((size_t)NHF * 2);
    __half* hB     = (__half*)alloc((size_t)NHF * 2);
    mfma_dense2<128, 128, 128, 128, 1, false, float, __half><<<GT, 256, 0, stream>>>(
        x, (const float*)nullptr, lin1_w, lin1_b, bn1_g, bn1_b, bn1_m, bn1_v, nullptr, h1);
    mfma_dense2<128, 128, 128, 128, 1, true, __half, __half, false, true>
        <<<GT, 256, 0, stream>>>(
        h1, (const __half*)nullptr, lin2_w, lin2_b, bn2_g, bn2_b, bn2_m, bn2_v, h1, base);
    // pass 1: get xs10
    const __half* cur = base;
    for (int k = 1; k <= KIT; ++k) {
      __half* nxt = (k & 1) ? hA : hB;
      prop_plane_kernel<<<GPROP, 256, 0, stream>>>(cur, base, row_start, csr, nxt);
      cur = nxt;
    }
    mfma_dense2<256, 128, 64, 64, 2, false, __half, __half, true, false>
        <<<GT, 256, 0, stream>>>(
        base, cur, att1_w, att1_b, nullptr, nullptr, nullptr, nullptr, nullptr, gbuf);
    att2_softmax_kernel<<<GA, 64, 0, stream>>>(gbuf, att2_w, att2_b, attw, NN);
    // pass 2: re-propagate, accumulate fused on the fly (fp32 accumulator)
    fused_accum_kernel<<<GP, 256, 0, stream>>>(base, attw, fusedF, 0);
    cur = base;
    for (int k = 1; k <= KIT; ++k) {
      __half* nxt = (k & 1) ? hA : hB;
      prop_plane_kernel<<<GPROP, 256, 0, stream>>>(cur, base, row_start, csr, nxt);
      fused_accum_kernel<<<GP, 256, 0, stream>>>(nxt, attw, fusedF, k);
      cur = nxt;
    }
    mfma_dense2<128, 128, 64, 64, 1, false, float, __half><<<GT, 256, 0, stream>>>(
        fusedF, (const float*)nullptr, head1_w, head1_b, bn3_g, bn3_b, bn3_m, bn3_v,
        nullptr, zbuf);
  }

  // head2 (z fp16 -> out fp32)
  mfma_dense2<64, 64, 48, 40, 0, false, __half, float><<<GT, 256, 0, stream>>>(
      zbuf, (const __half*)nullptr, head2_w, head2_b, nullptr, nullptr, nullptr, nullptr,
      nullptr, out);
}